// Round 2
// baseline (9642.192 us; speedup 1.0000x reference)
//
#include <hip/hip_runtime.h>
#include <math.h>

#define NN 100000
#define EE 1600000
#define HID 64

// Quad layout: 4 consecutive lanes own one edge/node; lane q owns output
// features [16q, 16q+16). Per-lane live state ~50 floats -> no spill
// (round-1 kernel spilled: VGPR=76 vs 192-float live set, 4.1 GB/dispatch
// of scratch traffic at 692 GB/s was the whole runtime).

__device__ __forceinline__ float silu_f(float x) {
    const float e = __expf(-x);
    return x * __builtin_amdgcn_rcpf(1.0f + e);
}

__device__ __forceinline__ void load16(float* dst, const float* __restrict__ src) {
#pragma unroll
    for (int c = 0; c < 4; ++c) {
        const float4 v = *reinterpret_cast<const float4*>(src + 4 * c);
        dst[4 * c + 0] = v.x; dst[4 * c + 1] = v.y;
        dst[4 * c + 2] = v.z; dst[4 * c + 3] = v.w;
    }
}

// acc[0..15] += x * w[0..15]   (w already offset to row k, column j0)
__device__ __forceinline__ void fma16(float* acc, const float x, const float* __restrict__ w) {
#pragma unroll
    for (int c = 0; c < 4; ++c) {
        const float4 v = *reinterpret_cast<const float4*>(w + 4 * c);
        acc[4 * c + 0] += x * v.x; acc[4 * c + 1] += x * v.y;
        acc[4 * c + 2] += x * v.z; acc[4 * c + 3] += x * v.w;
    }
}

// acc += xsrc[0..4*NV) @ W rows, W pre-offset to column j0 (row stride HID)
template <int NV>
__device__ __forceinline__ void seg(float* acc, const float4* __restrict__ xsrc,
                                    const float* __restrict__ w) {
#pragma unroll 1
    for (int c = 0; c < NV; ++c) {
        const float4 xv = xsrc[c];
        const float* wr = w + (size_t)(4 * c) * HID;
        fma16(acc, xv.x, wr);
        fma16(acc, xv.y, wr + HID);
        fma16(acc, xv.z, wr + 2 * HID);
        fma16(acc, xv.w, wr + 3 * HID);
    }
}

// acc[0..15] += (64-vector t, distributed 16-per-lane across the quad) @ W
// W pre-offset to column j0. Static register indexing throughout.
__device__ __forceinline__ void qgemm16(float* acc, const float* t_local,
                                        const float* __restrict__ w) {
#pragma unroll
    for (int ko = 0; ko < 4; ++ko) {
#pragma unroll
        for (int ki = 0; ki < 16; ++ki) {
            const float x = __shfl(t_local[ki], ko, 4);  // quad broadcast (DPP)
            fma16(acc, x, w + (size_t)(ko * 16 + ki) * HID);
        }
    }
}

__global__ void __launch_bounds__(256)
init_kernel(const float* __restrict__ pos, float* __restrict__ m_i,
            float* __restrict__ pos_out)
{
    const int i = blockIdx.x * 256 + threadIdx.x;
    const float4 z = make_float4(0.f, 0.f, 0.f, 0.f);
    if (i < NN * HID / 4) reinterpret_cast<float4*>(m_i)[i] = z;
    if (i < NN * 3 / 4)
        reinterpret_cast<float4*>(pos_out)[i] = reinterpret_cast<const float4*>(pos)[i];
}

__global__ void __launch_bounds__(256)
edge_kernel(const float* __restrict__ h, const float* __restrict__ pos,
            const float* __restrict__ ea, const float* __restrict__ te,
            const int* __restrict__ ei,
            const float* __restrict__ ew1, const float* __restrict__ eb1,
            const float* __restrict__ ew2, const float* __restrict__ eb2,
            const float* __restrict__ cw1, const float* __restrict__ cb1,
            const float* __restrict__ cw2,
            float* __restrict__ m_i, float* __restrict__ pos_out)
{
    const int tid = blockIdx.x * 256 + threadIdx.x;   // grid = EE*4/256 exactly
    const int e = tid >> 2;
    const int q = tid & 3;
    const int j0 = q << 4;

    const int row = ei[e];
    const int col = ei[EE + e];

    const float rx = pos[3 * row + 0] - pos[3 * col + 0];
    const float ry = pos[3 * row + 1] - pos[3 * col + 1];
    const float rz = pos[3 * row + 2] - pos[3 * col + 2];
    const float dist = sqrtf(rx * rx + ry * ry + rz * rz);

    // ---------- layer 1: edge_input[177] @ ew1 + eb1 (my 16 columns) ----------
    float acc[16];
    load16(acc, eb1 + j0);
    seg<16>(acc, reinterpret_cast<const float4*>(h + (size_t)row * HID), ew1 + j0);
    seg<16>(acc, reinterpret_cast<const float4*>(h + (size_t)col * HID),
            ew1 + (size_t)64 * HID + j0);
    seg<4>(acc, reinterpret_cast<const float4*>(ea + (size_t)e * 16),
           ew1 + (size_t)128 * HID + j0);
    fma16(acc, dist, ew1 + (size_t)144 * HID + j0);
    seg<8>(acc, reinterpret_cast<const float4*>(te + (size_t)row * 32),
           ew1 + (size_t)145 * HID + j0);

    float t[16];
#pragma unroll
    for (int i = 0; i < 16; ++i) t[i] = silu_f(acc[i]);

    // ---------- layer 2: silu(t @ ew2 + eb2) = m_ij slice ----------
    float acc2[16];
    load16(acc2, eb2 + j0);
    qgemm16(acc2, t, ew2 + j0);
    float m[16];
#pragma unroll
    for (int i = 0; i < 16; ++i) m[i] = silu_f(acc2[i]);

    // ---------- scatter m_ij into m_i[col] ----------
    float* md = m_i + (size_t)col * HID + j0;
#pragma unroll
    for (int i = 0; i < 16; ++i) unsafeAtomicAdd(md + i, m[i]);

    // ---------- coord MLP: silu(m @ cw1 + cb1) @ cw2 ----------
    float acc3[16];
    load16(acc3, cb1 + j0);
    qgemm16(acc3, m, cw1 + j0);

    float c2[16];
    load16(c2, cw2 + j0);
    float part = 0.0f;
#pragma unroll
    for (int i = 0; i < 16; ++i) part += silu_f(acc3[i]) * c2[i];
    part += __shfl_xor(part, 1, 4);
    part += __shfl_xor(part, 2, 4);

    const float s = part / (dist + 1e-8f);
    if (q < 3) {
        const float rc = (q == 0) ? rx : ((q == 1) ? ry : rz);
        unsafeAtomicAdd(&pos_out[3 * (size_t)col + q], s * rc);
    }
}

__global__ void __launch_bounds__(256)
node_kernel(const float* __restrict__ h, const float* __restrict__ te,
            const float* __restrict__ m_i,
            const float* __restrict__ nw1, const float* __restrict__ nb1,
            const float* __restrict__ nw2, const float* __restrict__ nb2,
            const float* __restrict__ sw, const float* __restrict__ sb,
            const float* __restrict__ tw, const float* __restrict__ tb,
            float* __restrict__ h_out)
{
    const int tid = blockIdx.x * 256 + threadIdx.x;
    const int n = tid >> 2;
    if (n >= NN) return;                 // whole quad drops together
    const int q = tid & 3;
    const int j0 = q << 4;

    const float4* tev = reinterpret_cast<const float4*>(te + (size_t)n * 32);

    // ---------- layer 1: [h, m_i, te] @ nw1 + nb1 ----------
    float acc[16];
    load16(acc, nb1 + j0);
    seg<16>(acc, reinterpret_cast<const float4*>(h + (size_t)n * HID), nw1 + j0);
    seg<16>(acc, reinterpret_cast<const float4*>(m_i + (size_t)n * HID),
            nw1 + (size_t)64 * HID + j0);
    seg<8>(acc, tev, nw1 + (size_t)128 * HID + j0);

    float t[16];
#pragma unroll
    for (int i = 0; i < 16; ++i) t[i] = silu_f(acc[i]);

    // ---------- layer 2: t @ nw2 + nb2 ----------
    float hu[16];
    load16(hu, nb2 + j0);
    qgemm16(hu, t, nw2 + j0);

    // ---------- FiLM scale: te @ sw + sb ----------
    float sc[16];
    load16(sc, sb + j0);
    seg<8>(sc, tev, sw + j0);

    // ---------- FiLM shift: te @ tw + tb ----------
    float sh[16];
    load16(sh, tb + j0);
    seg<8>(sh, tev, tw + j0);

    // ---------- h_new = h + sc*hu + sh ----------
    const float* hp = h + (size_t)n * HID + j0;
    float* op = h_out + (size_t)n * HID + j0;
#pragma unroll
    for (int c = 0; c < 4; ++c) {
        const float4 hx = *reinterpret_cast<const float4*>(hp + 4 * c);
        float4 o;
        o.x = hx.x + sc[4 * c + 0] * hu[4 * c + 0] + sh[4 * c + 0];
        o.y = hx.y + sc[4 * c + 1] * hu[4 * c + 1] + sh[4 * c + 1];
        o.z = hx.z + sc[4 * c + 2] * hu[4 * c + 2] + sh[4 * c + 2];
        o.w = hx.w + sc[4 * c + 3] * hu[4 * c + 3] + sh[4 * c + 3];
        *reinterpret_cast<float4*>(op + 4 * c) = o;
    }
}

extern "C" void kernel_launch(void* const* d_in, const int* in_sizes, int n_in,
                              void* d_out, int out_size, void* d_ws, size_t ws_size,
                              hipStream_t stream)
{
    const float* h    = (const float*)d_in[0];
    const float* pos  = (const float*)d_in[1];
    const float* ea   = (const float*)d_in[2];
    const float* te   = (const float*)d_in[3];
    const int*   ei   = (const int*)d_in[4];
    const float* ew1  = (const float*)d_in[5];
    const float* eb1  = (const float*)d_in[6];
    const float* ew2  = (const float*)d_in[7];
    const float* eb2  = (const float*)d_in[8];
    const float* nw1  = (const float*)d_in[9];
    const float* nb1  = (const float*)d_in[10];
    const float* nw2  = (const float*)d_in[11];
    const float* nb2  = (const float*)d_in[12];
    const float* cw1  = (const float*)d_in[13];
    const float* cb1  = (const float*)d_in[14];
    const float* cw2  = (const float*)d_in[15];
    const float* sw   = (const float*)d_in[16];
    const float* sb   = (const float*)d_in[17];
    const float* tw   = (const float*)d_in[18];
    const float* tb   = (const float*)d_in[19];

    float* h_out   = (float*)d_out;
    float* pos_out = (float*)d_out + (size_t)NN * HID;
    float* m_i     = (float*)d_ws;   // [N,64] accumulator

    init_kernel<<<(NN * HID / 4 + 255) / 256, 256, 0, stream>>>(pos, m_i, pos_out);

    edge_kernel<<<EE * 4 / 256, 256, 0, stream>>>(h, pos, ea, te, ei,
                                                  ew1, eb1, ew2, eb2,
                                                  cw1, cb1, cw2,
                                                  m_i, pos_out);

    node_kernel<<<(NN * 4 + 255) / 256, 256, 0, stream>>>(h, te, m_i,
                                                          nw1, nb1, nw2, nb2,
                                                          sw, sb, tw, tb, h_out);
}